// Round 3
// baseline (656.586 us; speedup 1.0000x reference)
//
#include <hip/hip_runtime.h>

#define G 4
#define S 2048
#define D 1024
#define E 32
#define TOPK 4
#define TPB 4                   // tokens per half-wave in the gemm kernel
#define NTOK (G * S)            // 8192 tokens
#define NROW (NTOK * E)         // 262144 (g,s,e) rows
#define ROWLEN 255              // floats per row (capacity-1)
#define HALF (NROW * ROWLEN)    // 66,846,720 floats per region

// tab[token*E + e] = { gate_bits, pos } ; pos in 1..255 = assigned, 0 = none.

// ---------------------------------------------------------------------------
// Kernel 1: gating GEMM + softmax + top-4. Half-wave (32 lanes, lane = expert)
// handles TPB=4 tokens: W fragments loaded once into registers, reused 4x
// -> W L2 traffic drops from 1 GB to 256 MB.
// ---------------------------------------------------------------------------
__global__ __launch_bounds__(256) void gemm_topk_kernel(
    const float* __restrict__ x, const float* __restrict__ W,
    const float* __restrict__ b,
    float* __restrict__ gate_ws, int* __restrict__ idx_ws,
    int2* __restrict__ tab)
{
    const int tid    = threadIdx.x;
    const int hw     = tid >> 5;                        // half-wave 0..7
    const int e      = tid & 31;
    const int token0 = (blockIdx.x * 8 + hw) * TPB;     // 4 consecutive tokens

#pragma unroll
    for (int t = 0; t < TPB; ++t)                        // zero-init table
        tab[(token0 + t) * E + e] = make_int2(0, 0);

    const float4* x4 = (const float4*)x;

    float acc[TPB] = {0.f, 0.f, 0.f, 0.f};
#pragma unroll 2
    for (int d4 = 0; d4 < D / 4; ++d4) {
        const float* wp = W + d4 * 4 * E + e;
        const float w0 = wp[0], w1 = wp[E], w2 = wp[2 * E], w3 = wp[3 * E];
#pragma unroll
        for (int t = 0; t < TPB; ++t) {
            float4 xv = x4[(long)(token0 + t) * (D / 4) + d4];
            acc[t] = fmaf(xv.x, w0,
                     fmaf(xv.y, w1,
                     fmaf(xv.z, w2,
                     fmaf(xv.w, w3, acc[t]))));
        }
    }
    const float bias = b[e];

#pragma unroll
    for (int t = 0; t < TPB; ++t) {
        const int token = token0 + t;
        const int g = token >> 11;
        const int s = token & (S - 1);
        float a = acc[t] + bias;

        // softmax across the 32 lanes of the half-wave
        float m = a;
#pragma unroll
        for (int off = 16; off >= 1; off >>= 1)
            m = fmaxf(m, __shfl_xor(m, off, 32));
        float ex = __expf(a - m);
        float sum = ex;
#pragma unroll
        for (int off = 16; off >= 1; off >>= 1)
            sum += __shfl_xor(sum, off, 32);
        float p = ex / sum;

        // top-4 by repeated argmax; ties -> lowest index
#pragma unroll
        for (int kk = 0; kk < TOPK; ++kk) {
            float v = p;
            int   vi = e;
#pragma unroll
            for (int off = 16; off >= 1; off >>= 1) {
                float ov = __shfl_xor(v, off, 32);
                int   oi = __shfl_xor(vi, off, 32);
                if (ov > v || (ov == v && oi < vi)) { v = ov; vi = oi; }
            }
            if (e == kk) {
                gate_ws[(kk * G + g) * S + s] = v;
                idx_ws [(kk * G + g) * S + s] = vi;
            }
            if (e == vi) p = -1.f;
        }
    }
}

// ---------------------------------------------------------------------------
// Kernel 2: positions via wave-ballot scan; one wave per (k,g) row (16 rows).
// Writes valid assignments {gate,pos} straight into the table.
// ---------------------------------------------------------------------------
__global__ __launch_bounds__(64) void positions_kernel(
    const int* __restrict__ idx_ws, const float* __restrict__ gate_ws,
    const int* __restrict__ cap_ptr, int2* __restrict__ tab)
{
    const int row  = blockIdx.x;          // row = k*G + g
    const int lane = threadIdx.x;         // 0..63
    const int cap  = *cap_ptr;            // 256
    const int g    = row & (G - 1);
    const int* idx = idx_ws + row * S;
    const float* gw = gate_ws + row * S;

    int cnt = 0;                          // running count for expert == lane
    const unsigned long long lowmask = (1ull << lane) - 1ull;

    for (int c = 0; c < S / 64; ++c) {
        const int s  = c * 64 + lane;
        const int my = idx[s];
        unsigned long long eqm = 0ull, mycol = 0ull;
#pragma unroll
        for (int ee = 0; ee < E; ++ee) {
            unsigned long long bal = __ballot(my == ee);
            if (my == ee)   eqm   = bal;
            if (lane == ee) mycol = bal;
        }
        const int prior = __shfl(cnt, my);
        const int pos = prior + __popcll(eqm & lowmask) + 1;
        if (pos < cap) {
            tab[(g * S + s) * E + my] = make_int2(__float_as_int(gw[s]), pos);
        }
        cnt += __popcll(mycol);
    }
}

// ---------------------------------------------------------------------------
// Kernel 3: single-pass output writer (touches each output float exactly once).
// ---------------------------------------------------------------------------
__global__ __launch_bounds__(256) void write_out_kernel(
    const int2* __restrict__ tab, float* __restrict__ out, int n)
{
    const int n4 = n >> 2;
    float4* out4 = (float4*)out;
    int i = blockIdx.x * blockDim.x + threadIdx.x;
    const int stride = gridDim.x * blockDim.x;

    for (; i < n4; i += stride) {
        const unsigned f = (unsigned)i << 2;
        const int region = f >= (unsigned)HALF;      // 0=combine, 1=dispatch
        const unsigned fp = region ? f - (unsigned)HALF : f;
        const unsigned r  = fp / 255u;               // (g,s,e) row
        const int p0 = (int)(fp - r * 255u);         // 0..254

        const int2 e0 = tab[r];
        const int2 e1 = tab[r + 1];                  // padded

        const float g0 = region ? 1.0f : __int_as_float(e0.x);
        const float g1 = region ? 1.0f : __int_as_float(e1.x);

        const int j0 = e0.y - 1 - p0;
        const int j1 = (e1.y > 0 && e1.y < 256) ? (e1.y + 254 - p0) : -1;

        float4 v;
        v.x = (j0 == 0) ? g0 : ((j1 == 0) ? g1 : 0.f);
        v.y = (j0 == 1) ? g0 : ((j1 == 1) ? g1 : 0.f);
        v.z = (j0 == 2) ? g0 : ((j1 == 2) ? g1 : 0.f);
        v.w = (j0 == 3) ? g0 : ((j1 == 3) ? g1 : 0.f);
        out4[i] = v;
    }
    if (blockIdx.x == 0 && threadIdx.x == 0) {
        for (int t = n4 << 2; t < n; ++t) out[t] = 0.f;   // loss scalar
    }
}

// ---------------------------------------------------------------------------
extern "C" void kernel_launch(void* const* d_in, const int* in_sizes, int n_in,
                              void* d_out, int out_size, void* d_ws, size_t ws_size,
                              hipStream_t stream)
{
    const float* x   = (const float*)d_in[0];
    const float* W   = (const float*)d_in[1];
    const float* b   = (const float*)d_in[2];
    const int*   cap = (const int*)d_in[3];
    float* out = (float*)d_out;

    const int NA = G * S * TOPK;                       // 32768 assignments
    int2*  tab     = (int2*)d_ws;                      // NROW+8 entries (pad)
    float* gate_ws = (float*)(tab + NROW + 8);
    int*   idx_ws  = (int*)(gate_ws + NA);

    gemm_topk_kernel<<<NTOK / (8 * TPB), 256, 0, stream>>>(x, W, b, gate_ws, idx_ws, tab);
    positions_kernel<<<G * TOPK, 64, 0, stream>>>(idx_ws, gate_ws, cap, tab);
    write_out_kernel<<<8192, 256, 0, stream>>>(tab, out, out_size);
}

// Round 5
// 653.266 us; speedup vs baseline: 1.0051x; 1.0051x over previous
//
#include <hip/hip_runtime.h>

#define G 4
#define S 2048
#define D 1024
#define E 32
#define TOPK 4
#define TPB 4                   // tokens per half-wave in the gemm kernel
#define NTOK (G * S)            // 8192 tokens
#define NROW (NTOK * E)         // 262144 (g,s,e) rows
#define ROWLEN 255              // floats per row (capacity-1)
#define HALF (NROW * ROWLEN)    // 66,846,720 floats per region

typedef float vf4 __attribute__((ext_vector_type(4)));   // native vector for nt-store

// tab[token*E + e] = { gate_bits, pos } ; pos in 1..255 = assigned, 0 = none.

// ---------------------------------------------------------------------------
// Kernel 1: gating GEMM + softmax + top-4. Half-wave (32 lanes, lane = expert)
// handles TPB=4 tokens: W fragments loaded once into registers, reused 4x.
// ---------------------------------------------------------------------------
__global__ __launch_bounds__(256) void gemm_topk_kernel(
    const float* __restrict__ x, const float* __restrict__ W,
    const float* __restrict__ b,
    float* __restrict__ gate_ws, int* __restrict__ idx_ws,
    int2* __restrict__ tab)
{
    const int tid    = threadIdx.x;
    const int hw     = tid >> 5;                        // half-wave 0..7
    const int e      = tid & 31;
    const int token0 = (blockIdx.x * 8 + hw) * TPB;

#pragma unroll
    for (int t = 0; t < TPB; ++t)                        // zero-init table
        tab[(token0 + t) * E + e] = make_int2(0, 0);

    const float4* x4 = (const float4*)x;

    float acc[TPB] = {0.f, 0.f, 0.f, 0.f};
#pragma unroll 2
    for (int d4 = 0; d4 < D / 4; ++d4) {
        const float* wp = W + d4 * 4 * E + e;
        const float w0 = wp[0], w1 = wp[E], w2 = wp[2 * E], w3 = wp[3 * E];
#pragma unroll
        for (int t = 0; t < TPB; ++t) {
            float4 xv = x4[(long)(token0 + t) * (D / 4) + d4];
            acc[t] = fmaf(xv.x, w0,
                     fmaf(xv.y, w1,
                     fmaf(xv.z, w2,
                     fmaf(xv.w, w3, acc[t]))));
        }
    }
    const float bias = b[e];

#pragma unroll
    for (int t = 0; t < TPB; ++t) {
        const int token = token0 + t;
        const int g = token >> 11;
        const int s = token & (S - 1);
        float a = acc[t] + bias;

        float m = a;
#pragma unroll
        for (int off = 16; off >= 1; off >>= 1)
            m = fmaxf(m, __shfl_xor(m, off, 32));
        float ex = __expf(a - m);
        float sum = ex;
#pragma unroll
        for (int off = 16; off >= 1; off >>= 1)
            sum += __shfl_xor(sum, off, 32);
        float p = ex / sum;

#pragma unroll
        for (int kk = 0; kk < TOPK; ++kk) {
            float v = p;
            int   vi = e;
#pragma unroll
            for (int off = 16; off >= 1; off >>= 1) {
                float ov = __shfl_xor(v, off, 32);
                int   oi = __shfl_xor(vi, off, 32);
                if (ov > v || (ov == v && oi < vi)) { v = ov; vi = oi; }
            }
            if (e == kk) {
                gate_ws[(kk * G + g) * S + s] = v;
                idx_ws [(kk * G + g) * S + s] = vi;
            }
            if (e == vi) p = -1.f;
        }
    }
}

// ---------------------------------------------------------------------------
// Kernel 2: positions via wave-ballot scan; one wave per (k,g) row (16 rows).
// All 32 chunks preloaded into registers -> one load latency, not 32.
// ---------------------------------------------------------------------------
__global__ __launch_bounds__(64) void positions_kernel(
    const int* __restrict__ idx_ws, const float* __restrict__ gate_ws,
    const int* __restrict__ cap_ptr, int2* __restrict__ tab)
{
    const int row  = blockIdx.x;          // row = k*G + g
    const int lane = threadIdx.x;         // 0..63
    const int cap  = *cap_ptr;            // 256
    const int g    = row & (G - 1);
    const int* idx = idx_ws + row * S;
    const float* gw = gate_ws + row * S;

    int   myv[S / 64];
    float myg[S / 64];
#pragma unroll
    for (int c = 0; c < S / 64; ++c) {
        myv[c] = idx[c * 64 + lane];
        myg[c] = gw [c * 64 + lane];
    }

    int cnt = 0;                          // running count for expert == lane
    const unsigned long long lowmask = (1ull << lane) - 1ull;

#pragma unroll 4
    for (int c = 0; c < S / 64; ++c) {
        const int s  = c * 64 + lane;
        const int my = myv[c];
        unsigned long long eqm = 0ull, mycol = 0ull;
#pragma unroll
        for (int ee = 0; ee < E; ++ee) {
            unsigned long long bal = __ballot(my == ee);
            if (my == ee)   eqm   = bal;
            if (lane == ee) mycol = bal;
        }
        const int prior = __shfl(cnt, my);
        const int pos = prior + __popcll(eqm & lowmask) + 1;
        if (pos < cap) {
            tab[(g * S + s) * E + my] = make_int2(__float_as_int(myg[c]), pos);
        }
        cnt += __popcll(mycol);
    }
}

// ---------------------------------------------------------------------------
// Kernel 3: single-pass output writer, nontemporal stores (write floor 535 MB).
// ---------------------------------------------------------------------------
__global__ __launch_bounds__(256) void write_out_kernel(
    const int2* __restrict__ tab, float* __restrict__ out, int n)
{
    const int n4 = n >> 2;
    vf4* out4 = (vf4*)out;
    int i = blockIdx.x * blockDim.x + threadIdx.x;
    const int stride = gridDim.x * blockDim.x;

    for (; i < n4; i += stride) {
        const unsigned f = (unsigned)i << 2;
        const int region = f >= (unsigned)HALF;      // 0=combine, 1=dispatch
        const unsigned fp = region ? f - (unsigned)HALF : f;
        const unsigned r  = fp / 255u;               // (g,s,e) row
        const int p0 = (int)(fp - r * 255u);         // 0..254

        const int2 e0 = tab[r];
        const int2 e1 = tab[r + 1];                  // padded

        const float g0 = region ? 1.0f : __int_as_float(e0.x);
        const float g1 = region ? 1.0f : __int_as_float(e1.x);

        const int j0 = e0.y - 1 - p0;
        const int j1 = (e1.y > 0 && e1.y < 256) ? (e1.y + 254 - p0) : -1;

        vf4 v;
        v.x = (j0 == 0) ? g0 : ((j1 == 0) ? g1 : 0.f);
        v.y = (j0 == 1) ? g0 : ((j1 == 1) ? g1 : 0.f);
        v.z = (j0 == 2) ? g0 : ((j1 == 2) ? g1 : 0.f);
        v.w = (j0 == 3) ? g0 : ((j1 == 3) ? g1 : 0.f);
        __builtin_nontemporal_store(v, &out4[i]);
    }
    if (blockIdx.x == 0 && threadIdx.x == 0) {
        for (int t = n4 << 2; t < n; ++t) out[t] = 0.f;   // loss scalar
    }
}

// ---------------------------------------------------------------------------
extern "C" void kernel_launch(void* const* d_in, const int* in_sizes, int n_in,
                              void* d_out, int out_size, void* d_ws, size_t ws_size,
                              hipStream_t stream)
{
    const float* x   = (const float*)d_in[0];
    const float* W   = (const float*)d_in[1];
    const float* b   = (const float*)d_in[2];
    const int*   cap = (const int*)d_in[3];
    float* out = (float*)d_out;

    const int NA = G * S * TOPK;                       // 32768 assignments
    int2*  tab     = (int2*)d_ws;                      // NROW+8 entries (pad)
    float* gate_ws = (float*)(tab + NROW + 8);
    int*   idx_ws  = (int*)(gate_ws + NA);

    gemm_topk_kernel<<<NTOK / (8 * TPB), 256, 0, stream>>>(x, W, b, gate_ws, idx_ws, tab);
    positions_kernel<<<G * TOPK, 64, 0, stream>>>(idx_ws, gate_ws, cap, tab);
    write_out_kernel<<<8192, 256, 0, stream>>>(tab, out, out_size);
}